// Round 15
// baseline (1449.545 us; speedup 1.0000x reference)
//
#include <hip/hip_runtime.h>

#define TT 2048
#define HH 64
#define II 6
#define OO 6
#define NTHR 1024   // 16 waves: 4 L0 | 4 XG | 4 L1 | 4 FC  (4 waves/SIMD)

typedef float    f32x4 __attribute__((ext_vector_type(4)));
typedef float    f32x2 __attribute__((ext_vector_type(2)));
typedef _Float16 f16x8 __attribute__((ext_vector_type(8)));

__device__ __forceinline__ float fast_sig(float v) {
    return __builtin_amdgcn_rcpf(1.0f + __expf(-v));
}
__device__ __forceinline__ float fast_tanh(float v) {
    return 1.0f - 2.0f * __builtin_amdgcn_rcpf(__expf(2.0f * v) + 1.0f);
}

#define MFMA(a, b, c) __builtin_amdgcn_mfma_f32_16x16x32_f16((a), (b), (c), 0, 0, 0)

// LDS-only barrier: global loads/stores stay in flight across it.
#define LGKM_BARRIER() asm volatile("s_waitcnt lgkmcnt(0)\ns_barrier" ::: "memory")

__global__
__attribute__((amdgpu_flat_work_group_size(NTHR, NTHR)))
__attribute__((amdgpu_waves_per_eu(4, 4)))   // pin 4 waves/SIMD -> 128 VGPR budget
void lstm_mfma_kernel(const float* __restrict__ x,
                      const float* __restrict__ Wih0, const float* __restrict__ Whh0,
                      const float* __restrict__ b0,
                      const float* __restrict__ Wih1, const float* __restrict__ Whh1,
                      const float* __restrict__ b1,
                      const float* __restrict__ W1, const float* __restrict__ bf1,
                      const float* __restrict__ W2, const float* __restrict__ bf2,
                      float* __restrict__ out)
{
    const int row  = blockIdx.x;      // one batch row per block
    const int tid  = threadIdx.x;
    const int wid  = tid >> 6;        // wave id 0..15
    const int lane = tid & 63;
    const int n    = lane & 15;       // MFMA col-lane (B-col / D-col)
    const int q    = lane >> 4;       // k-group: elems k = 8q..8q+7 (+32 for hi chunk)
    const int role = wid >> 2;        // 0=L0 (layer0), 1=XG (xg1), 2=L1 (layer1), 3=FC
    const int w    = wid & 3;         // role-local wave index: unit block 16w..16w+15

    __shared__ __attribute__((aligned(16))) _Float16 H0[2][HH];
    __shared__ __attribute__((aligned(16))) _Float16 H1[2][HH];
    __shared__ __attribute__((aligned(16))) _Float16 Rb[2][HH];
    __shared__ __attribute__((aligned(16))) float    XG[2][4 * HH];  // xg1 strip, f32

    if (tid < HH) {
        H0[0][tid] = (_Float16)0.f; H0[1][tid] = (_Float16)0.f;
        H1[0][tid] = (_Float16)0.f; H1[1][tid] = (_Float16)0.f;
        Rb[0][tid] = (_Float16)0.f; Rb[1][tid] = (_Float16)0.f;
    }
    if (tid < 2 * 4 * HH) XG[0][tid] = 0.f;   // covers both slots (flat aliasing)

    // elem i <-> k = kbase + 8q + i (same map for A-frag reads, so it cancels)
    auto mk = [&](const float* W, int r, int ld, int kbase, int kmax, bool rok) {
        f16x8 f;
        #pragma unroll
        for (int i = 0; i < 8; ++i) {
            int kk = kbase + 8 * q + i;
            f[i] = (rok && kk < kmax) ? (_Float16)W[r * ld + kk] : (_Float16)0.f;
        }
        return f;
    };
    auto splat = [](float v) { f32x4 r = {v, v, v, v}; return r; };
    const f32x4 zero4 = {0.f, 0.f, 0.f, 0.f};

    f16x8 fragG[8], fragX[2], fragY[2];
    f32x4 biasv[4], biasX = zero4, biasY = zero4;
    float b0j[4] = {0.f, 0.f, 0.f, 0.f};
    float wx[4][6];
    #pragma unroll
    for (int g = 0; g < 4; ++g) {
        biasv[g] = zero4;
        #pragma unroll
        for (int k2 = 0; k2 < 6; ++k2) wx[g][k2] = 0.f;
    }

    if (role == 0) {            // layer0: Whh0 rows (4 gates x units 16w+n)
        #pragma unroll
        for (int g = 0; g < 4; ++g) {
            const int r0 = g * HH + 16 * w + n;
            fragG[2 * g + 0] = mk(Whh0, r0, HH, 0,  HH, true);
            fragG[2 * g + 1] = mk(Whh0, r0, HH, 32, HH, true);
            b0j[g] = b0[r0];
            #pragma unroll
            for (int k2 = 0; k2 < 6; ++k2) wx[g][k2] = Wih0[r0 * II + k2];
        }
        fragX[0] = fragG[0]; fragX[1] = fragG[1];
        fragY[0] = fragG[0]; fragY[1] = fragG[1];
    } else if (role == 1) {     // xg1: Wih1 rows, bias b1 as C-init
        #pragma unroll
        for (int g = 0; g < 4; ++g) {
            const int r0 = g * HH + 16 * w + n;
            fragG[2 * g + 0] = mk(Wih1, r0, HH, 0,  HH, true);
            fragG[2 * g + 1] = mk(Wih1, r0, HH, 32, HH, true);
            biasv[g] = splat(b1[r0]);
        }
        fragX[0] = fragG[0]; fragX[1] = fragG[1];
        fragY[0] = fragG[0]; fragY[1] = fragG[1];
    } else if (role == 2) {     // layer1: Whh1 rows (xg added as scalar)
        #pragma unroll
        for (int g = 0; g < 4; ++g) {
            const int r0 = g * HH + 16 * w + n;
            fragG[2 * g + 0] = mk(Whh1, r0, HH, 0,  HH, true);
            fragG[2 * g + 1] = mk(Whh1, r0, HH, 32, HH, true);
        }
        fragX[0] = fragG[0]; fragX[1] = fragG[1];
        fragY[0] = fragG[0]; fragY[1] = fragG[1];
    } else {                    // FC: W1 rows 16w+n ; FC2 (w0): W2 row n
        const int rf = 16 * w + n;
        fragX[0] = mk(W1, rf, HH, 0,  HH, true);
        fragX[1] = mk(W1, rf, HH, 32, HH, true);
        biasX = splat(bf1[rf]);
        fragY[0] = mk(W2, n, HH, 0,  HH, n < OO);
        fragY[1] = mk(W2, n, HH, 32, HH, n < OO);
        biasY = splat((n < OO) ? bf2[n] : 0.f);
        #pragma unroll
        for (int i = 0; i < 8; ++i) fragG[i] = fragX[0];
    }

    // x pointer opaqued to VGPR: forces vector (vmcnt) loads, keeps them lazy
    const float* xrow = x + (size_t)row * TT * II;
    {
        unsigned long long p = (unsigned long long)xrow;
        asm volatile("" : "+v"(p));
        xrow = (const float*)p;
    }
    f32x4 xc03 = {0.f, 0.f, 0.f, 0.f};
    f32x2 xc45 = {0.f, 0.f};
    if (role == 0) {            // preload x[0]
        xc03 = *reinterpret_cast<const f32x4*>(xrow);
        xc45 = *reinterpret_cast<const f32x2*>(xrow + 4);
    }

    float* outrow = out + (size_t)row * TT * OO;
    float cst = 0.f;   // cell state: L0 lanes 0-15 hold c0; L1 lanes 0-15 hold c1

    __syncthreads();

    // Slot algebra (writes at epoch e visible at epoch e+1 after the barrier):
    //  H0: L0 writes step t  -> slot t&1;  L0/XG read h0[t-1] -> slot (t+1)&1  OK
    //  XG: XG writes step t-1 -> slot (t+1)&1; L1 reads step s2=t-2 -> slot t&1 OK
    //  H1: L1 writes s2=t-2 -> slot t&1; L1/FC read h1[t-3] -> slot (t+1)&1     OK
    //  Rb: FC writes s3=t-3 -> slot (t+1)&1; FC2 reads s4=t-4 -> slot t&1       OK
    for (int t = 0; t <= TT + 3; ++t) {
        const int sp = (t + 1) & 1;
        const int sc = t & 1;

        if (role == 0) {            // ---- layer0 @ step t
            const int tn = (t + 1 < TT) ? t + 1 : TT - 1;
            const float* xp = xrow + (size_t)tn * II;
            f32x4 xn03 = *reinterpret_cast<const f32x4*>(xp);
            f32x2 xn45 = *reinterpret_cast<const f32x2*>(xp + 4);

            const f16x8 a0 = *reinterpret_cast<const f16x8*>(&H0[sp][8 * q]);
            const f16x8 a1 = *reinterpret_cast<const f16x8*>(&H0[sp][32 + 8 * q]);
            float gv[4];
            #pragma unroll
            for (int g = 0; g < 4; ++g) {
                f32x4 acc0 = MFMA(a0, fragG[2 * g + 0], zero4);
                f32x4 acc1 = MFMA(a1, fragG[2 * g + 1], zero4);
                float xd = b0j[g];
                xd = fmaf(wx[g][0], xc03[0], xd); xd = fmaf(wx[g][1], xc03[1], xd);
                xd = fmaf(wx[g][2], xc03[2], xd); xd = fmaf(wx[g][3], xc03[3], xd);
                xd = fmaf(wx[g][4], xc45[0], xd); xd = fmaf(wx[g][5], xc45[1], xd);
                gv[g] = (acc0[0] + acc1[0]) + xd;
            }
            if (t < TT) {
                float i_ = fast_sig(gv[0]), f_ = fast_sig(gv[1]);
                float g_ = fast_tanh(gv[2]), o_ = fast_sig(gv[3]);
                cst = f_ * cst + i_ * g_;
                float h = o_ * fast_tanh(cst);
                if (lane < 16) H0[sc][16 * w + lane] = (_Float16)h;
            }
            xc03 = xn03;   // vmcnt wait lands next iter
            xc45 = xn45;
        } else if (role == 1) {     // ---- xg1 @ step t-1 (reads h0[t-1])
            const f16x8 a0 = *reinterpret_cast<const f16x8*>(&H0[sp][8 * q]);
            const f16x8 a1 = *reinterpret_cast<const f16x8*>(&H0[sp][32 + 8 * q]);
            #pragma unroll
            for (int g = 0; g < 4; ++g) {
                f32x4 acc0 = MFMA(a0, fragG[2 * g + 0], biasv[g]);
                f32x4 acc1 = MFMA(a1, fragG[2 * g + 1], zero4);
                if (t >= 1 && t <= TT && lane < 16)
                    XG[sp][g * HH + 16 * w + lane] = acc0[0] + acc1[0];
            }
        } else if (role == 2) {     // ---- layer1 @ s2 = t-2
            const int s2 = t - 2;
            const f16x8 a0 = *reinterpret_cast<const f16x8*>(&H1[sp][8 * q]);
            const f16x8 a1 = *reinterpret_cast<const f16x8*>(&H1[sp][32 + 8 * q]);
            float gv[4];
            #pragma unroll
            for (int g = 0; g < 4; ++g) {
                const float xgv = XG[sc][g * HH + 16 * w + n];
                f32x4 acc0 = MFMA(a0, fragG[2 * g + 0], zero4);
                f32x4 acc1 = MFMA(a1, fragG[2 * g + 1], zero4);
                gv[g] = (acc0[0] + acc1[0]) + xgv;
            }
            if (s2 >= 0 && s2 < TT) {
                float i_ = fast_sig(gv[0]), f_ = fast_sig(gv[1]);
                float g_ = fast_tanh(gv[2]), o_ = fast_sig(gv[3]);
                cst = f_ * cst + i_ * g_;
                float h = o_ * fast_tanh(cst);
                if (lane < 16) H1[sc][16 * w + lane] = (_Float16)h;
            }
        } else {                    // ---- FC1 @ s3 = t-3 ; FC2 @ s4 = t-4 (w==0)
            const int s3 = t - 3, s4 = t - 4;
            const f16x8 a0 = *reinterpret_cast<const f16x8*>(&H1[sp][8 * q]);
            const f16x8 a1 = *reinterpret_cast<const f16x8*>(&H1[sp][32 + 8 * q]);
            f32x4 f0 = MFMA(a0, fragX[0], biasX);
            f32x4 f1 = MFMA(a1, fragX[1], zero4);
            if (s3 >= 0 && s3 < TT && lane < 16)
                Rb[sp][16 * w + lane] = (_Float16)fmaxf(f0[0] + f1[0], 0.f);
            if (w == 0) {
                const f16x8 r0 = *reinterpret_cast<const f16x8*>(&Rb[sc][8 * q]);
                const f16x8 r1 = *reinterpret_cast<const f16x8*>(&Rb[sc][32 + 8 * q]);
                f32x4 o0 = MFMA(r0, fragY[0], biasY);
                f32x4 o1 = MFMA(r1, fragY[1], zero4);
                if (s4 >= 0 && s4 < TT && lane < OO)
                    outrow[(size_t)s4 * OO + lane] = o0[0] + o1[0];
            }
        }
        LGKM_BARRIER();   // LDS-only drain; global ops stay in flight
    }
}

extern "C" void kernel_launch(void* const* d_in, const int* in_sizes, int n_in,
                              void* d_out, int out_size, void* d_ws, size_t ws_size,
                              hipStream_t stream) {
    const float* xp   = (const float*)d_in[0];
    const float* Wih0 = (const float*)d_in[1];
    const float* Whh0 = (const float*)d_in[2];
    const float* b0   = (const float*)d_in[3];
    const float* Wih1 = (const float*)d_in[4];
    const float* Whh1 = (const float*)d_in[5];
    const float* b1   = (const float*)d_in[6];
    const float* W1   = (const float*)d_in[7];
    const float* bf1  = (const float*)d_in[8];
    const float* W2   = (const float*)d_in[9];
    const float* bf2  = (const float*)d_in[10];
    float* outp = (float*)d_out;

    lstm_mfma_kernel<<<dim3(256), dim3(NTHR), 0, stream>>>(
        xp, Wih0, Whh0, b0, Wih1, Whh1, b1, W1, bf1, W2, bf2, outp);
}